// Round 1
// baseline (53.041 us; speedup 1.0000x reference)
//
#include <hip/hip_runtime.h>

// FWHT over last dim (4096) of (x * seed), scaled by 1/64.
// One wave (64 threads) per row. 64 f32 registers per thread.
// Phase 1: in-register butterflies over j bits 0..5.
// One swizzled LDS transpose (16 KB), then Phase 2 over j bits 6..11.
// LDS swizzle: w(j) = j ^ (((j>>6)&7)<<2)  (bijective, bank-conflict-free).

#define N 4096

__global__ __launch_bounds__(64) void fwht64_kernel(
    const float* __restrict__ x,
    const float* __restrict__ seed,
    float* __restrict__ out)
{
    extern __shared__ float lds[];        // 4096 floats = 16 KB
    const int l = threadIdx.x;            // lane 0..63
    const long long row = blockIdx.x;

    const float* xr = x + row * (long long)N;
    float* outr = out + row * (long long)N;

    float v[64];

    // ---- Load + seed multiply: v[m] <-> j = 64*l + m, m = 4q + c ----
    const float4* x4 = reinterpret_cast<const float4*>(xr) + l * 16;
    const float4* s4 = reinterpret_cast<const float4*>(seed) + l * 16;
#pragma unroll
    for (int q = 0; q < 16; ++q) {
        float4 a = x4[q];
        float4 b = s4[q];
        v[4 * q + 0] = a.x * b.x;
        v[4 * q + 1] = a.y * b.y;
        v[4 * q + 2] = a.z * b.z;
        v[4 * q + 3] = a.w * b.w;
    }

    // ---- Phase 1: FWHT over reg index (j bits 0..5), strides 1..32 ----
#pragma unroll
    for (int s = 1; s < 64; s <<= 1) {
#pragma unroll
        for (int m = 0; m < 64; ++m) {
            if (!(m & s)) {
                float a = v[m], b = v[m | s];
                v[m]     = a + b;
                v[m | s] = a - b;
            }
        }
    }

    // ---- LDS exchange with XOR swizzle w(j) = j ^ (((j>>6)&7)<<2) ----
    // Write: j = 64*l + m (m = 4q+c) -> float4 slot 16*l + (q ^ (l&7)).
    float4* lds4 = reinterpret_cast<float4*>(lds);
#pragma unroll
    for (int q = 0; q < 16; ++q) {
        int qq = q ^ (l & 7);
        lds4[l * 16 + qq] = make_float4(v[4 * q + 0], v[4 * q + 1],
                                        v[4 * q + 2], v[4 * q + 3]);
    }
    __syncthreads();
    // Read: j = 64*r + l -> word 64*r + (l ^ (4*(r&7))).
#pragma unroll
    for (int r = 0; r < 64; ++r) {
        v[r] = lds[64 * r + (l ^ (4 * (r & 7)))];
    }

    // ---- Phase 2: FWHT over reg index (j bits 6..11), strides 1..32 ----
#pragma unroll
    for (int s = 1; s < 64; s <<= 1) {
#pragma unroll
        for (int m = 0; m < 64; ++m) {
            if (!(m & s)) {
                float a = v[m], b = v[m | s];
                v[m]     = a + b;
                v[m | s] = a - b;
            }
        }
    }

    // ---- Store: out[64*r + l] = v[r] / 64  (perfectly coalesced) ----
#pragma unroll
    for (int r = 0; r < 64; ++r) {
        outr[64 * r + l] = v[r] * 0.015625f;
    }
}

extern "C" void kernel_launch(void* const* d_in, const int* in_sizes, int n_in,
                              void* d_out, int out_size, void* d_ws, size_t ws_size,
                              hipStream_t stream)
{
    const float* x    = (const float*)d_in[0];
    const float* seed = (const float*)d_in[1];
    float* out        = (float*)d_out;

    const int rows = in_sizes[0] / N;   // 8192
    dim3 grid(rows), block(64);
    size_t shmem = N * sizeof(float);   // 16 KB
    fwht64_kernel<<<grid, block, shmem, stream>>>(x, seed, out);
}

// Round 2
// 51.525 us; speedup vs baseline: 1.0294x; 1.0294x over previous
//
#include <hip/hip_runtime.h>

// FWHT over last dim (4096) of (x * seed), scaled by 1/64.
// One wave (64 threads) per block; each block processes 4 rows, software-
// pipelined: row i+1's 16 float4 loads are issued before row i's compute,
// hiding HBM latency under the ~2000-cycle butterfly network.
// Seed (16 KB, shared by all rows) is hoisted to registers once per block.
// Per row: radix-64 in registers (j bits 0..5), one swizzled 16 KB LDS
// transpose (w(j) = j ^ (((j>>6)&7)<<2), bank-conflict-free, verified R1),
// radix-64 over j bits 6..11, coalesced dword stores.

#define N 4096

__global__ __launch_bounds__(64) void fwht64_pipe_kernel(
    const float* __restrict__ x,
    const float* __restrict__ seed,
    float* __restrict__ out)
{
    __shared__ float lds[N];              // 16 KB transpose scratch
    const int l = threadIdx.x;            // lane 0..63
    const long long row0 = (long long)blockIdx.x * 4;

    // ---- seed -> 64 registers, once per block ----
    const float4* s4 = reinterpret_cast<const float4*>(seed) + l * 16;
    float sv[64];
#pragma unroll
    for (int q = 0; q < 16; ++q) {
        float4 t = s4[q];
        sv[4*q+0] = t.x; sv[4*q+1] = t.y; sv[4*q+2] = t.z; sv[4*q+3] = t.w;
    }

    const float4* xb = reinterpret_cast<const float4*>(x)
                       + row0 * (N / 4) + (long long)l * 16;
    float4* lds4 = reinterpret_cast<float4*>(lds);

    float va[64], vb[64];

    // Issue 16 float4 loads for row r into dst (all independent -> in flight).
#define LOADROW(dst, r)                                                  \
    {                                                                    \
        _Pragma("unroll")                                                \
        for (int q = 0; q < 16; ++q) {                                   \
            float4 t = xb[(r) * (N / 4) + q];                            \
            dst[4*q+0] = t.x; dst[4*q+1] = t.y;                          \
            dst[4*q+2] = t.z; dst[4*q+3] = t.w;                          \
        }                                                                \
    }

    // Full per-row FWHT on register set v (consumes the prefetched data).
#define COMPUTEROW(v, r)                                                 \
    {                                                                    \
        _Pragma("unroll")                                                \
        for (int m = 0; m < 64; ++m) v[m] *= sv[m];                      \
        _Pragma("unroll")                                                \
        for (int s = 1; s < 64; s <<= 1) {                               \
            _Pragma("unroll")                                            \
            for (int m = 0; m < 64; ++m) if (!(m & s)) {                 \
                float p0 = v[m], p1 = v[m | s];                          \
                v[m] = p0 + p1; v[m | s] = p0 - p1;                      \
            }                                                            \
        }                                                                \
        __syncthreads(); /* prev row's LDS reads done before overwrite */\
        _Pragma("unroll")                                                \
        for (int q = 0; q < 16; ++q) {                                   \
            int qq = q ^ (l & 7);                                        \
            lds4[l * 16 + qq] = make_float4(v[4*q+0], v[4*q+1],          \
                                            v[4*q+2], v[4*q+3]);         \
        }                                                                \
        __syncthreads();                                                 \
        _Pragma("unroll")                                                \
        for (int rr = 0; rr < 64; ++rr)                                  \
            v[rr] = lds[64 * rr + (l ^ (4 * (rr & 7)))];                 \
        _Pragma("unroll")                                                \
        for (int s = 1; s < 64; s <<= 1) {                               \
            _Pragma("unroll")                                            \
            for (int m = 0; m < 64; ++m) if (!(m & s)) {                 \
                float p0 = v[m], p1 = v[m | s];                          \
                v[m] = p0 + p1; v[m | s] = p0 - p1;                      \
            }                                                            \
        }                                                                \
        float* o = out + (row0 + (r)) * (long long)N;                    \
        _Pragma("unroll")                                                \
        for (int rr = 0; rr < 64; ++rr)                                  \
            o[64 * rr + l] = v[rr] * 0.015625f;                          \
    }

    // 2-deep software pipeline over the block's 4 rows.
    LOADROW(va, 0)
    LOADROW(vb, 1)
    COMPUTEROW(va, 0)
    LOADROW(va, 2)
    COMPUTEROW(vb, 1)
    LOADROW(vb, 3)
    COMPUTEROW(va, 2)
    COMPUTEROW(vb, 3)

#undef LOADROW
#undef COMPUTEROW
}

extern "C" void kernel_launch(void* const* d_in, const int* in_sizes, int n_in,
                              void* d_out, int out_size, void* d_ws, size_t ws_size,
                              hipStream_t stream)
{
    const float* x    = (const float*)d_in[0];
    const float* seed = (const float*)d_in[1];
    float* out        = (float*)d_out;

    const int rows = in_sizes[0] / N;     // 8192
    dim3 grid(rows / 4), block(64);       // 4 rows per block
    fwht64_pipe_kernel<<<grid, block, 0, stream>>>(x, seed, out);
}